// Round 1
// baseline (643.573 us; speedup 1.0000x reference)
//
#include <hip/hip_runtime.h>
#include <math.h>

// ---------------------------------------------------------------------------
// GAT_23613730193923 — full fp32 implementation (round 1: correctness-first)
// B=1024, N=80 (PAST=64, FUT=16), feat=51, MLP 51->128->128->50
// ---------------------------------------------------------------------------

#define NEGBIG (-1e30f)

// ---- workspace offsets (floats). Total = 7,524,421 floats ~= 30.1 MB ----
#define OFF_X     0          // B*80*51 = 4177920   (x = [mlp_out, data_last])
#define OFF_X1    4177920    // B*64*50 = 3276800   (xk past rows = x1)
#define OFF_YH    7454720    // B*16
#define OFF_A     7471104    // 80*80
#define OFF_AN11  7477504    // 64*64
#define OFF_AN22  7481600    // 16*16
#define OFF_TH    7481856    // 50*50
#define OFF_MK    7484356    // 16*64 (Atsoft>=0.004 mask)
#define OFF_W1T   7485380    // 51*128
#define OFF_W2T   7491908    // 128*128
#define OFF_W3T   7508292    // 128*50
#define OFF_G1AT  7514692    // 51*64
#define OFF_G1BT  7517956    // 64*50
#define OFF_G2AT  7521156    // 51*64
#define OFF_SC    7524420    // 1  (-0.5 / (sigmoid(sm)*0.01))

// ---- output offsets (floats): (out B*16, dist B*6400, A 6400) ----
#define OUT_OUT   0
#define OUT_DIST  16384
#define OUT_A     6569984

// ===========================================================================
// k_prep: A/An/mask/theta + weight transposes. 4 blocks x 256.
// ===========================================================================
__global__ __launch_bounds__(256) void k_prep(
    const float* __restrict__ M, const float* __restrict__ Wk,
    const float* __restrict__ sm,
    const float* __restrict__ w1, const float* __restrict__ w2,
    const float* __restrict__ w3,
    const float* __restrict__ wg1a, const float* __restrict__ wg1b,
    const float* __restrict__ wg2a,
    float* __restrict__ ws, float* __restrict__ out)
{
  __shared__ float Msh[80 * 26];
  __shared__ float Ash[80 * 80];
  __shared__ float d1[64];
  __shared__ float d2s[16];
  const int t = threadIdx.x;

  if (blockIdx.x == 0) {
    for (int e = t; e < 80 * 26; e += 256) Msh[e] = M[e];
    __syncthreads();
    // A0 = relu(M M^T), strictly-lower entries only (mask = tril(-1))
    for (int e = t; e < 6400; e += 256) {
      int i = e / 80, j = e % 80;
      float v = 0.f;
      if (j < i) {
        float s = 0.f;
        for (int k = 0; k < 26; ++k) s += Msh[i * 26 + k] * Msh[j * 26 + k];
        v = s > 0.f ? s : 0.f;
      }
      Ash[e] = v;
    }
    __syncthreads();
    // row softmax over j<i; row 0 stays all-zero (masked-then-zeroed)
    if (t > 0 && t < 80) {
      int i = t;
      float m = -3.4e38f;
      for (int j = 0; j < i; ++j) m = fmaxf(m, Ash[i * 80 + j]);
      float s = 0.f;
      for (int j = 0; j < i; ++j) {
        float e = expf(Ash[i * 80 + j] - m);
        Ash[i * 80 + j] = e;
        s += e;
      }
      float inv = 1.f / s;
      for (int j = 0; j < i; ++j) Ash[i * 80 + j] *= inv;
    }
    __syncthreads();
    {
      float* Aws = ws + OFF_A;
      float* Aout = out + OUT_A;
      for (int e = t; e < 6400; e += 256) { Aws[e] = Ash[e]; Aout[e] = Ash[e]; }
    }
    // degrees: d = (1 + count(A>1e-15 row-wise))^-0.5 on A11 / A22
    if (t < 64) {
      int c = 0;
      for (int j = 0; j < 64; ++j) if (Ash[t * 80 + j] > 1e-15f) ++c;
      d1[t] = 1.f / sqrtf(1.f + (float)c);
    } else if (t < 80) {
      int i = t - 64; int c = 0;
      for (int j = 0; j < 16; ++j) if (Ash[(64 + i) * 80 + 64 + j] > 1e-15f) ++c;
      d2s[i] = 1.f / sqrtf(1.f + (float)c);
    }
    __syncthreads();
    {
      float* an11 = ws + OFF_AN11;
      float* an22 = ws + OFF_AN22;
      for (int e = t; e < 4096; e += 256) {
        int i = e >> 6, j = e & 63;
        an11[e] = d1[i] * Ash[i * 80 + j] * d1[j];
      }
      for (int e = t; e < 256; e += 256) {
        int i = e >> 4, j = e & 15;
        an22[e] = d2s[i] * Ash[(64 + i) * 80 + 64 + j] * d2s[j];
      }
    }
    // mask: softmax over i of At row j (At = A[64+j, 0:64], !=0 masking), >= 0.004
    if (t < 16) {
      float* mk = ws + OFF_MK;
      int j = t;
      float m = -3.4e38f;
      for (int i = 0; i < 64; ++i) {
        float v = Ash[(64 + j) * 80 + i];
        v = (v != 0.f) ? v : NEGBIG;
        m = fmaxf(m, v);
      }
      float s = 0.f;
      for (int i = 0; i < 64; ++i) {
        float v = Ash[(64 + j) * 80 + i];
        v = (v != 0.f) ? v : NEGBIG;
        s += expf(v - m);
      }
      float inv = 1.f / s;
      for (int i = 0; i < 64; ++i) {
        float v = Ash[(64 + j) * 80 + i];
        v = (v != 0.f) ? v : NEGBIG;
        mk[j * 64 + i] = (expf(v - m) * inv >= 0.004f) ? 1.f : 0.f;
      }
    }
  } else if (blockIdx.x == 1) {
    // theta = Wk Wk^T (symmetric by construction; (T+T^T)/2 is identity here)
    float* th = ws + OFF_TH;
    for (int e = t; e < 2500; e += 256) {
      int i = e / 50, j = e % 50;
      float s = 0.f;
      for (int k = 0; k < 64; ++k) s += Wk[i * 64 + k] * Wk[j * 64 + k];
      th[e] = s;
    }
    if (t == 0) {
      float v = sm[0];
      float sig = 1.f / (1.f + expf(-v));
      (ws + OFF_SC)[0] = -0.5f / (sig * 0.01f);
    }
  } else if (blockIdx.x == 2) {
    float* w1t = ws + OFF_W1T; float* w3t = ws + OFF_W3T; float* g1at = ws + OFF_G1AT;
    for (int e = t; e < 128 * 51; e += 256) { int o = e / 51, k = e % 51; w1t[k * 128 + o] = w1[e]; }
    for (int e = t; e < 50 * 128; e += 256) { int o = e / 128, k = e % 128; w3t[k * 50 + o] = w3[e]; }
    for (int e = t; e < 64 * 51; e += 256) { int o = e / 51, k = e % 51; g1at[k * 64 + o] = wg1a[e]; }
  } else {
    float* w2t = ws + OFF_W2T; float* g1bt = ws + OFF_G1BT; float* g2at = ws + OFF_G2AT;
    for (int e = t; e < 128 * 128; e += 256) { int o = e / 128, k = e % 128; w2t[k * 128 + o] = w2[e]; }
    for (int e = t; e < 50 * 64; e += 256) { int o = e / 64, k = e % 64; g1bt[k * 50 + o] = wg1b[e]; }
    for (int e = t; e < 64 * 51; e += 256) { int o = e / 51, k = e % 51; g2at[k * 64 + o] = wg2a[e]; }
  }
}

// ===========================================================================
// k_mlp: embedding gather + 3-layer MLP. 32 rows/block, 2560 blocks x 256.
// Each thread: 4 rows x 4 outs register tile; W read from global (L1/L2 hot).
// ===========================================================================
template <int K, bool RELU>
__device__ __forceinline__ void mlp_layer(const float* __restrict__ inS, int inStride,
                                          const float* __restrict__ Wt,
                                          const float* __restrict__ bias,
                                          float* __restrict__ outS, int outStride, int t)
{
  const int r0 = (t >> 5) * 4;   // 8 row groups
  const int o0 = (t & 31) * 4;   // 32 col groups (128 outs)
  float acc[4][4] = {{0.f}};
  for (int k = 0; k < K; ++k) {
    const float4 w = *(const float4*)(Wt + k * 128 + o0);
    float a[4];
#pragma unroll
    for (int i = 0; i < 4; ++i) a[i] = inS[(r0 + i) * inStride + k];
#pragma unroll
    for (int i = 0; i < 4; ++i) {
      acc[i][0] += a[i] * w.x; acc[i][1] += a[i] * w.y;
      acc[i][2] += a[i] * w.z; acc[i][3] += a[i] * w.w;
    }
  }
  const float4 bb = *(const float4*)(bias + o0);
  const float bv[4] = {bb.x, bb.y, bb.z, bb.w};
#pragma unroll
  for (int i = 0; i < 4; ++i) {
#pragma unroll
    for (int j = 0; j < 4; ++j) {
      float v = acc[i][j] + bv[j];
      if (RELU) v = v > 0.f ? v : 0.f;
      outS[(r0 + i) * outStride + o0 + j] = v;
    }
  }
}

__global__ __launch_bounds__(256) void k_mlp(
    const float* __restrict__ data,
    const float* __restrict__ emb0, const float* __restrict__ emb1,
    const float* __restrict__ emb2,
    const float* __restrict__ b1, const float* __restrict__ b2,
    const float* __restrict__ b3,
    float* __restrict__ ws)
{
  __shared__ __align__(16) float sIn[32 * 52];
  __shared__ __align__(16) float sH1[32 * 132];
  __shared__ __align__(16) float sH2[32 * 132];
  const int t = threadIdx.x;
  const int base = blockIdx.x * 32;
  const float* w1t = ws + OFF_W1T;
  const float* w2t = ws + OFF_W2T;
  const float* w3t = ws + OFF_W3T;
  float* x = ws + OFF_X;

  // gather: [emb0(32), emb1(8), emb2(8), data cols 3..5] -> 51 features
  for (int e = t; e < 32 * 51; e += 256) {
    int r = e / 51, c = e % 51;
    int g = base + r;
    float v;
    if (c < 32)      { int i0 = (int)data[g * 6 + 0]; v = emb0[i0 * 32 + c]; }
    else if (c < 40) { int i1 = (int)data[g * 6 + 1]; v = emb1[i1 * 8 + (c - 32)]; }
    else if (c < 48) { int i2 = (int)data[g * 6 + 2]; v = emb2[i2 * 8 + (c - 40)]; }
    else             { v = data[g * 6 + 3 + (c - 48)]; }
    sIn[r * 52 + c] = v;
  }
  __syncthreads();
  mlp_layer<51, true>(sIn, 52, w1t, b1, sH1, 132, t);
  __syncthreads();
  mlp_layer<128, true>(sH1, 132, w2t, b2, sH2, 132, t);
  __syncthreads();
  // layer 3: 50 outs, ragged 8 groups of <=7
  {
    const int r = t >> 3;
    const int og = t & 7;
    const int o0 = og * 7;
    const int nv = (o0 + 7 <= 50) ? 7 : (50 - o0);
    float acc[7] = {0.f, 0.f, 0.f, 0.f, 0.f, 0.f, 0.f};
    for (int k = 0; k < 128; ++k) {
      float hv = sH2[r * 132 + k];
#pragma unroll
      for (int j = 0; j < 7; ++j)
        if (j < nv) acc[j] += hv * w3t[k * 50 + o0 + j];
    }
    int g = base + r;
    for (int j = 0; j < nv; ++j) x[g * 51 + o0 + j] = acc[j] + b3[o0 + j];
    if (og == 0) x[g * 51 + 50] = data[g * 6 + 5];  // x[...,50] = data last col
  }
}

// ===========================================================================
// k_g1: per-batch GCN stack on past nodes.
// x1 = ((An @ relu(An @ (sg1 @ W1aT))) @ W1bT)   [re-associated outer gcnn]
// ===========================================================================
template <int K, bool RELU>
__device__ __forceinline__ void gemm_tile68(const float* __restrict__ Am,
                                            const float* __restrict__ Bm,
                                            float* __restrict__ Cm, int t)
{
  const int r0 = (t >> 4) * 4, o0 = (t & 15) * 4;
  float acc[4][4] = {{0.f}};
  for (int k = 0; k < K; ++k) {
    const float4 b4 = *(const float4*)(Bm + k * 68 + o0);
    float a[4];
#pragma unroll
    for (int i = 0; i < 4; ++i) a[i] = Am[(r0 + i) * 68 + k];
#pragma unroll
    for (int i = 0; i < 4; ++i) {
      acc[i][0] += a[i] * b4.x; acc[i][1] += a[i] * b4.y;
      acc[i][2] += a[i] * b4.z; acc[i][3] += a[i] * b4.w;
    }
  }
#pragma unroll
  for (int i = 0; i < 4; ++i) {
#pragma unroll
    for (int j = 0; j < 4; ++j) {
      float v = acc[i][j];
      if (RELU) v = v > 0.f ? v : 0.f;
      Cm[(r0 + i) * 68 + o0 + j] = v;
    }
  }
}

__global__ __launch_bounds__(256) void k_g1(float* __restrict__ ws)
{
  __shared__ __align__(16) float B0[64 * 68];
  __shared__ __align__(16) float B1[64 * 68];
  __shared__ __align__(16) float B2[64 * 68];
  const int t = threadIdx.x, b = blockIdx.x;
  const float* x = ws + OFF_X;
  const float* an11 = ws + OFF_AN11;
  const float* g1at = ws + OFF_G1AT;
  const float* g1bt = ws + OFF_G1BT;
  float* x1 = ws + OFF_X1;

  for (int e = t; e < 64 * 51; e += 256) {
    int r = e / 51, c = e % 51;
    B0[r * 68 + c] = x[(b * 80 + r) * 51 + c];
  }
  for (int e = t; e < 51 * 64; e += 256) B1[(e / 64) * 68 + (e & 63)] = g1at[e];
  __syncthreads();
  gemm_tile68<51, false>(B0, B1, B2, t);        // t1 = sg1 @ W1aT   (64x64)
  __syncthreads();
  for (int e = t; e < 4096; e += 256) B1[(e >> 6) * 68 + (e & 63)] = an11[e];
  __syncthreads();
  gemm_tile68<64, true>(B1, B2, B0, t);         // P = relu(An @ t1) (64x64)
  __syncthreads();
  gemm_tile68<64, false>(B1, B0, B2, t);        // Q = An @ P        (64x64)
  __syncthreads();
  for (int e = t; e < 64 * 50; e += 256) {
    int k = e / 50, o = e % 50;
    B0[k * 68 + o] = g1bt[e];
  }
  __syncthreads();
  // x1 = Q @ W1bT  (64x50), straight to global
  {
    const int r0 = (t >> 4) * 4, o0 = (t & 15) * 4;
    float acc[4][4] = {{0.f}};
    for (int k = 0; k < 64; ++k) {
      const float4 b4 = *(const float4*)(B0 + k * 68 + o0);
      float a[4];
#pragma unroll
      for (int i = 0; i < 4; ++i) a[i] = B2[(r0 + i) * 68 + k];
#pragma unroll
      for (int i = 0; i < 4; ++i) {
        acc[i][0] += a[i] * b4.x; acc[i][1] += a[i] * b4.y;
        acc[i][2] += a[i] * b4.z; acc[i][3] += a[i] * b4.w;
      }
    }
#pragma unroll
    for (int i = 0; i < 4; ++i) {
#pragma unroll
      for (int j = 0; j < 4; ++j) {
        int o = o0 + j;
        if (o < 50) x1[(b * 64 + r0 + i) * 50 + o] = acc[i][j];
      }
    }
  }
}

// ===========================================================================
// k_q: q decomposition + masked softmax over FUT axis (axis=1!) + yh.
// q[j,i] = xp_i'T xp_i + xf_j'T xf_j - 2 xp_i'T xf_j  (T=theta)
// ===========================================================================
__global__ __launch_bounds__(256) void k_q(float* __restrict__ ws)
{
  __shared__ float Xp[64 * 53];
  __shared__ float Xf[16 * 53];
  __shared__ float Th[50 * 53];
  __shared__ float U[64 * 53];
  __shared__ float V[16 * 53];
  __shared__ float yv[64];
  __shared__ float sv[64];
  __shared__ float rv[16];
  __shared__ float al[16 * 64];
  __shared__ float mks[16 * 64];
  const int t = threadIdx.x, b = blockIdx.x;
  const float* x = ws + OFF_X;
  const float* x1 = ws + OFF_X1;
  const float* th = ws + OFF_TH;
  const float* mk = ws + OFF_MK;
  const float sc = (ws + OFF_SC)[0];
  float* yh = ws + OFF_YH;

  for (int e = t; e < 64 * 50; e += 256) { int r = e / 50, c = e % 50; Xp[r * 53 + c] = x1[(b * 64 + r) * 50 + c]; }
  for (int e = t; e < 16 * 50; e += 256) { int r = e / 50, c = e % 50; Xf[r * 53 + c] = x[(b * 80 + 64 + r) * 51 + c]; }
  for (int e = t; e < 2500; e += 256)    { int r = e / 50, c = e % 50; Th[r * 53 + c] = th[e]; }
  for (int e = t; e < 1024; e += 256)    mks[e] = mk[e];
  if (t < 64) yv[t] = x[(b * 80 + t) * 51 + 50];
  __syncthreads();
  // U = Xp @ Th (64x50), V = Xf @ Th (16x50)
  {
    const int r0 = (t >> 4) * 4, o0 = (t & 15) * 4;
    float acc[4][4] = {{0.f}};
    for (int k = 0; k < 50; ++k) {
      float bb[4];
#pragma unroll
      for (int j = 0; j < 4; ++j) bb[j] = Th[k * 53 + o0 + j];
      float a[4];
#pragma unroll
      for (int i = 0; i < 4; ++i) a[i] = Xp[(r0 + i) * 53 + k];
#pragma unroll
      for (int i = 0; i < 4; ++i)
#pragma unroll
        for (int j = 0; j < 4; ++j) acc[i][j] += a[i] * bb[j];
    }
#pragma unroll
    for (int i = 0; i < 4; ++i)
#pragma unroll
      for (int j = 0; j < 4; ++j) {
        int o = o0 + j;
        if (o < 50) U[(r0 + i) * 53 + o] = acc[i][j];
      }
    const int jr = t >> 4;
    float accv[4] = {0.f, 0.f, 0.f, 0.f};
    for (int k = 0; k < 50; ++k) {
      float a = Xf[jr * 53 + k];
#pragma unroll
      for (int j = 0; j < 4; ++j) accv[j] += a * Th[k * 53 + o0 + j];
    }
#pragma unroll
    for (int j = 0; j < 4; ++j) {
      int o = o0 + j;
      if (o < 50) V[jr * 53 + o] = accv[j];
    }
  }
  __syncthreads();
  if (t < 64) {
    float s = 0.f;
    for (int k = 0; k < 50; ++k) s += U[t * 53 + k] * Xp[t * 53 + k];
    sv[t] = s;
  } else if (t < 80) {
    int j = t - 64; float s = 0.f;
    for (int k = 0; k < 50; ++k) s += V[j * 53 + k] * Xf[j * 53 + k];
    rv[j] = s;
  }
  __syncthreads();
  // logits al[j][i] = sc * (s_i + r_j - 2 * U_i . Xf_j)
  {
    const int i = t & 63;
    const int j0 = (t >> 6) * 4;
#pragma unroll
    for (int jj = 0; jj < 4; ++jj) {
      int j = j0 + jj;
      float d = 0.f;
      for (int k = 0; k < 50; ++k) d += U[i * 53 + k] * Xf[j * 53 + k];
      al[j * 64 + i] = sc * (sv[i] + rv[j] - 2.f * d);
    }
  }
  __syncthreads();
  // softmax over j (the FUT axis) per (b,i); all-masked -> uniform 1/16
  if (t < 64) {
    const int i = t;
    float m = -3.4e38f;
#pragma unroll
    for (int j = 0; j < 16; ++j) {
      float v = (mks[j * 64 + i] != 0.f) ? al[j * 64 + i] : NEGBIG;
      m = fmaxf(m, v);
    }
    float s = 0.f; float ex[16];
#pragma unroll
    for (int j = 0; j < 16; ++j) {
      float v = (mks[j * 64 + i] != 0.f) ? al[j * 64 + i] : NEGBIG;
      ex[j] = expf(v - m); s += ex[j];
    }
    float inv = 1.f / s;
#pragma unroll
    for (int j = 0; j < 16; ++j) al[j * 64 + i] = ex[j] * inv;
  }
  __syncthreads();
  if (t < 16) {
    float s = 0.f;
    for (int i = 0; i < 64; ++i) s += al[t * 64 + i] * yv[i];
    yh[b * 16 + t] = s;
  }
}

// ===========================================================================
// k_g2: future-node GCN stack -> out (B x 16)
// ===========================================================================
__global__ __launch_bounds__(256) void k_g2(const float* __restrict__ wg2b,
                                            float* __restrict__ ws,
                                            float* __restrict__ out)
{
  __shared__ float X2[16 * 53];
  __shared__ __align__(16) float G[16 * 68];
  __shared__ float P[16 * 68];
  __shared__ float A22[256];
  __shared__ float wb[64];
  __shared__ float z[16];
  const int t = threadIdx.x, b = blockIdx.x;
  const float* x = ws + OFF_X;
  const float* yh = ws + OFF_YH;
  const float* an22 = ws + OFF_AN22;
  const float* g2at = ws + OFF_G2AT;

  for (int e = t; e < 16 * 51; e += 256) {
    int r = e / 51, c = e % 51;
    X2[r * 53 + c] = (c < 50) ? x[(b * 80 + 64 + r) * 51 + c] : yh[b * 16 + r];
  }
  for (int e = t; e < 256; e += 256) A22[e] = an22[e];
  if (t < 64) wb[t] = wg2b[t];
  __syncthreads();
  // G = X2 @ W2aT (16x64)
  {
    const int j = t >> 4, o0 = (t & 15) * 4;
    float acc[4] = {0.f, 0.f, 0.f, 0.f};
    for (int k = 0; k < 51; ++k) {
      float a = X2[j * 53 + k];
      const float4 w = *(const float4*)(g2at + k * 64 + o0);
      acc[0] += a * w.x; acc[1] += a * w.y; acc[2] += a * w.z; acc[3] += a * w.w;
    }
#pragma unroll
    for (int q2 = 0; q2 < 4; ++q2) G[j * 68 + o0 + q2] = acc[q2];
  }
  __syncthreads();
  // P = relu(An22 @ G)
  {
    const int j = t >> 4, o0 = (t & 15) * 4;
    float acc[4] = {0.f, 0.f, 0.f, 0.f};
    for (int k = 0; k < 16; ++k) {
      float a = A22[j * 16 + k];
      const float4 g4 = *(const float4*)(G + k * 68 + o0);
      acc[0] += a * g4.x; acc[1] += a * g4.y; acc[2] += a * g4.z; acc[3] += a * g4.w;
    }
#pragma unroll
    for (int q2 = 0; q2 < 4; ++q2) {
      float v = acc[q2];
      P[j * 68 + o0 + q2] = v > 0.f ? v : 0.f;
    }
  }
  __syncthreads();
  if (t < 16) {
    float s = 0.f;
    for (int o = 0; o < 64; ++o) s += P[t * 68 + o] * wb[o];
    z[t] = s;
  }
  __syncthreads();
  if (t < 16) {
    float s = 0.f;
#pragma unroll
    for (int k = 0; k < 16; ++k) s += A22[t * 16 + k] * z[k];
    out[OUT_OUT + b * 16 + t] = s;
  }
}

// ===========================================================================
// k_dist: pairwise distances over xc=[sg1, x2] (80x51 per batch)
// ===========================================================================
__global__ __launch_bounds__(256) void k_dist(float* __restrict__ ws,
                                              float* __restrict__ out)
{
  __shared__ float Xc[80 * 53];
  __shared__ float sq[80];
  const int t = threadIdx.x, b = blockIdx.x;
  const float* x = ws + OFF_X;
  const float* yh = ws + OFF_YH;
  float* dist = out + OUT_DIST + b * 6400;

  for (int e = t; e < 80 * 51; e += 256) {
    int n = e / 51, c = e % 51;
    float v;
    if (n < 64 || c < 50) v = x[(b * 80 + n) * 51 + c];
    else                  v = yh[b * 16 + (n - 64)];
    Xc[n * 53 + c] = v;
  }
  __syncthreads();
  if (t < 80) {
    float s = 0.f;
    for (int c = 0; c < 51; ++c) { float v = Xc[t * 53 + c]; s += v * v; }
    sq[t] = s;
  }
  __syncthreads();
  const int n0 = (t >> 4) * 5, m0 = (t & 15) * 5;
  float acc[5][5] = {{0.f}};
  for (int k = 0; k < 51; ++k) {
    float av[5], bv[5];
#pragma unroll
    for (int i = 0; i < 5; ++i) av[i] = Xc[(n0 + i) * 53 + k];
#pragma unroll
    for (int j = 0; j < 5; ++j) bv[j] = Xc[(m0 + j) * 53 + k];
#pragma unroll
    for (int i = 0; i < 5; ++i)
#pragma unroll
      for (int j = 0; j < 5; ++j) acc[i][j] += av[i] * bv[j];
  }
#pragma unroll
  for (int i = 0; i < 5; ++i) {
#pragma unroll
    for (int j = 0; j < 5; ++j) {
      float d2 = sq[n0 + i] + sq[m0 + j] - 2.f * acc[i][j];
      d2 = d2 > 0.f ? d2 : 0.f;
      dist[(n0 + i) * 80 + (m0 + j)] = d2 > 0.f ? sqrtf(d2) : 0.f;
    }
  }
}

// ===========================================================================
extern "C" void kernel_launch(void* const* d_in, const int* in_sizes, int n_in,
                              void* d_out, int out_size, void* d_ws, size_t ws_size,
                              hipStream_t stream)
{
  const float* data = (const float*)d_in[0];
  const float* emb0 = (const float*)d_in[1];
  const float* emb1 = (const float*)d_in[2];
  const float* emb2 = (const float*)d_in[3];
  const float* w1   = (const float*)d_in[4];
  const float* b1   = (const float*)d_in[5];
  const float* w2   = (const float*)d_in[6];
  const float* b2   = (const float*)d_in[7];
  const float* w3   = (const float*)d_in[8];
  const float* b3   = (const float*)d_in[9];
  const float* M    = (const float*)d_in[10];
  const float* wg1a = (const float*)d_in[11];
  const float* wg1b = (const float*)d_in[12];
  const float* Wk   = (const float*)d_in[13];
  const float* smo  = (const float*)d_in[14];
  const float* wg2a = (const float*)d_in[15];
  const float* wg2b = (const float*)d_in[16];
  float* ws  = (float*)d_ws;
  float* out = (float*)d_out;

  k_prep<<<dim3(4),    dim3(256), 0, stream>>>(M, Wk, smo, w1, w2, w3, wg1a, wg1b, wg2a, ws, out);
  k_mlp <<<dim3(2560), dim3(256), 0, stream>>>(data, emb0, emb1, emb2, b1, b2, b3, ws);
  k_g1  <<<dim3(1024), dim3(256), 0, stream>>>(ws);
  k_q   <<<dim3(1024), dim3(256), 0, stream>>>(ws);
  k_g2  <<<dim3(1024), dim3(256), 0, stream>>>(wg2b, ws, out);
  k_dist<<<dim3(1024), dim3(256), 0, stream>>>(ws, out);
}

// Round 2
// 375.829 us; speedup vs baseline: 1.7124x; 1.7124x over previous
//
#include <hip/hip_runtime.h>
#include <math.h>

// ---------------------------------------------------------------------------
// GAT_23613730193923 — fp32, round 2: LDS-staged weights + float4 k-loops
// B=1024, N=80 (PAST=64, FUT=16), feat=51, MLP 51->128->128->50
// ---------------------------------------------------------------------------

#define NEGBIG (-1e30f)

// ---- workspace offsets (floats) ----
#define OFF_X     0          // B*80*51 = 4177920
#define OFF_X1    4177920    // B*64*50 = 3276800
#define OFF_YH    7454720    // B*16
#define OFF_A     7471104    // 80*80
#define OFF_AN11  7477504    // 64*64
#define OFF_AN22  7481600    // 16*16
#define OFF_TH    7481856    // 50*50
#define OFF_MK    7484356    // 16*64
#define OFF_W1T   7485380    // 51*128  [k][o]
#define OFF_W2T   7491908    // 128*128 [k][o]
#define OFF_W3T   7508292    // 128*50  [k][o]
#define OFF_G1AT  7514692    // 51*64
#define OFF_G1BT  7517956    // 64*50
#define OFF_G2AT  7521156    // 51*64
#define OFF_SC    7524420    // 1

// ---- output offsets (floats): (out B*16, dist B*6400, A 6400) ----
#define OUT_OUT   0
#define OUT_DIST  16384
#define OUT_A     6569984

// ===========================================================================
// k_prep (unchanged from round 1)
// ===========================================================================
__global__ __launch_bounds__(256) void k_prep(
    const float* __restrict__ M, const float* __restrict__ Wk,
    const float* __restrict__ sm,
    const float* __restrict__ w1, const float* __restrict__ w2,
    const float* __restrict__ w3,
    const float* __restrict__ wg1a, const float* __restrict__ wg1b,
    const float* __restrict__ wg2a,
    float* __restrict__ ws, float* __restrict__ out)
{
  __shared__ float Msh[80 * 26];
  __shared__ float Ash[80 * 80];
  __shared__ float d1[64];
  __shared__ float d2s[16];
  const int t = threadIdx.x;

  if (blockIdx.x == 0) {
    for (int e = t; e < 80 * 26; e += 256) Msh[e] = M[e];
    __syncthreads();
    for (int e = t; e < 6400; e += 256) {
      int i = e / 80, j = e % 80;
      float v = 0.f;
      if (j < i) {
        float s = 0.f;
        for (int k = 0; k < 26; ++k) s += Msh[i * 26 + k] * Msh[j * 26 + k];
        v = s > 0.f ? s : 0.f;
      }
      Ash[e] = v;
    }
    __syncthreads();
    if (t > 0 && t < 80) {
      int i = t;
      float m = -3.4e38f;
      for (int j = 0; j < i; ++j) m = fmaxf(m, Ash[i * 80 + j]);
      float s = 0.f;
      for (int j = 0; j < i; ++j) {
        float e = expf(Ash[i * 80 + j] - m);
        Ash[i * 80 + j] = e;
        s += e;
      }
      float inv = 1.f / s;
      for (int j = 0; j < i; ++j) Ash[i * 80 + j] *= inv;
    }
    __syncthreads();
    {
      float* Aws = ws + OFF_A;
      float* Aout = out + OUT_A;
      for (int e = t; e < 6400; e += 256) { Aws[e] = Ash[e]; Aout[e] = Ash[e]; }
    }
    if (t < 64) {
      int c = 0;
      for (int j = 0; j < 64; ++j) if (Ash[t * 80 + j] > 1e-15f) ++c;
      d1[t] = 1.f / sqrtf(1.f + (float)c);
    } else if (t < 80) {
      int i = t - 64; int c = 0;
      for (int j = 0; j < 16; ++j) if (Ash[(64 + i) * 80 + 64 + j] > 1e-15f) ++c;
      d2s[i] = 1.f / sqrtf(1.f + (float)c);
    }
    __syncthreads();
    {
      float* an11 = ws + OFF_AN11;
      float* an22 = ws + OFF_AN22;
      for (int e = t; e < 4096; e += 256) {
        int i = e >> 6, j = e & 63;
        an11[e] = d1[i] * Ash[i * 80 + j] * d1[j];
      }
      for (int e = t; e < 256; e += 256) {
        int i = e >> 4, j = e & 15;
        an22[e] = d2s[i] * Ash[(64 + i) * 80 + 64 + j] * d2s[j];
      }
    }
    if (t < 16) {
      float* mk = ws + OFF_MK;
      int j = t;
      float m = -3.4e38f;
      for (int i = 0; i < 64; ++i) {
        float v = Ash[(64 + j) * 80 + i];
        v = (v != 0.f) ? v : NEGBIG;
        m = fmaxf(m, v);
      }
      float s = 0.f;
      for (int i = 0; i < 64; ++i) {
        float v = Ash[(64 + j) * 80 + i];
        v = (v != 0.f) ? v : NEGBIG;
        s += expf(v - m);
      }
      float inv = 1.f / s;
      for (int i = 0; i < 64; ++i) {
        float v = Ash[(64 + j) * 80 + i];
        v = (v != 0.f) ? v : NEGBIG;
        mk[j * 64 + i] = (expf(v - m) * inv >= 0.004f) ? 1.f : 0.f;
      }
    }
  } else if (blockIdx.x == 1) {
    float* th = ws + OFF_TH;
    for (int e = t; e < 2500; e += 256) {
      int i = e / 50, j = e % 50;
      float s = 0.f;
      for (int k = 0; k < 64; ++k) s += Wk[i * 64 + k] * Wk[j * 64 + k];
      th[e] = s;
    }
    if (t == 0) {
      float v = sm[0];
      float sig = 1.f / (1.f + expf(-v));
      (ws + OFF_SC)[0] = -0.5f / (sig * 0.01f);
    }
  } else if (blockIdx.x == 2) {
    float* w1t = ws + OFF_W1T; float* w3t = ws + OFF_W3T; float* g1at = ws + OFF_G1AT;
    for (int e = t; e < 128 * 51; e += 256) { int o = e / 51, k = e % 51; w1t[k * 128 + o] = w1[e]; }
    for (int e = t; e < 50 * 128; e += 256) { int o = e / 128, k = e % 128; w3t[k * 50 + o] = w3[e]; }
    for (int e = t; e < 64 * 51; e += 256) { int o = e / 51, k = e % 51; g1at[k * 64 + o] = wg1a[e]; }
  } else {
    float* w2t = ws + OFF_W2T; float* g1bt = ws + OFF_G1BT; float* g2at = ws + OFF_G2AT;
    for (int e = t; e < 128 * 128; e += 256) { int o = e / 128, k = e % 128; w2t[k * 128 + o] = w2[e]; }
    for (int e = t; e < 50 * 64; e += 256) { int o = e / 64, k = e % 64; g1bt[k * 50 + o] = wg1b[e]; }
    for (int e = t; e < 64 * 51; e += 256) { int o = e / 51, k = e % 51; g2at[k * 64 + o] = wg2a[e]; }
  }
}

// ===========================================================================
// k_mlp v2: all weights staged via one LDS buffer; float4 k-loops; h in one
// reused 32x132 LDS buffer. LDS = 56.8KB -> 2 blocks/CU.
// ===========================================================================
__global__ __launch_bounds__(256) void k_mlp(
    const float* __restrict__ data,
    const float* __restrict__ emb0, const float* __restrict__ emb1,
    const float* __restrict__ emb2,
    const float* __restrict__ b1, const float* __restrict__ b2,
    const float* __restrict__ b3,
    float* __restrict__ ws)
{
  __shared__ __align__(16) float sIn[32 * 52];   // 6.6 KB
  __shared__ __align__(16) float sH[32 * 132];   // 16.9 KB (h1 then h2)
  __shared__ __align__(16) float sW[6656];       // 26.6 KB (W1 / W2-chunk / W3)
  const int t = threadIdx.x;
  const int base = blockIdx.x * 32;
  const float* w1t = ws + OFF_W1T;
  const float* w2t = ws + OFF_W2T;
  const float* w3t = ws + OFF_W3T;
  float* x = ws + OFF_X;

  // ---- gather 32x51 + zero pad col 51 ----
  for (int e = t; e < 32 * 51; e += 256) {
    int r = e / 51, c = e % 51;
    int g = base + r;
    float v;
    if (c < 32)      { int i0 = (int)data[g * 6 + 0]; v = emb0[i0 * 32 + c]; }
    else if (c < 40) { int i1 = (int)data[g * 6 + 1]; v = emb1[i1 * 8 + (c - 32)]; }
    else if (c < 48) { int i2 = (int)data[g * 6 + 2]; v = emb2[i2 * 8 + (c - 40)]; }
    else             { v = data[g * 6 + 3 + (c - 48)]; }
    sIn[r * 52 + c] = v;
  }
  for (int r = t; r < 32; r += 256) sIn[r * 52 + 51] = 0.f;
  // ---- load W1 -> sW[52][128] (row 51 zero) ----
  for (int e = t; e < 1632; e += 256) ((float4*)sW)[e] = ((const float4*)w1t)[e];
  for (int e = t; e < 128; e += 256) sW[6528 + e] = 0.f;
  __syncthreads();

  const int r0 = (t >> 5) * 4;   // 8 groups x 4 rows = 32
  const int o0 = (t & 31) * 4;   // 128 outs

  // ---- layer 1: h1 = relu(sIn @ W1 + b1) ----
  float acc[4][4] = {{0.f}};
  for (int kk = 0; kk < 52; kk += 4) {
    float4 a[4], w[4];
#pragma unroll
    for (int i = 0; i < 4; ++i) a[i] = *(const float4*)(sIn + (r0 + i) * 52 + kk);
#pragma unroll
    for (int q = 0; q < 4; ++q) w[q] = *(const float4*)(sW + (kk + q) * 128 + o0);
#pragma unroll
    for (int i = 0; i < 4; ++i) {
      const float ak[4] = {a[i].x, a[i].y, a[i].z, a[i].w};
#pragma unroll
      for (int q = 0; q < 4; ++q) {
        acc[i][0] += ak[q] * w[q].x; acc[i][1] += ak[q] * w[q].y;
        acc[i][2] += ak[q] * w[q].z; acc[i][3] += ak[q] * w[q].w;
      }
    }
  }
  {
    const float4 bb = *(const float4*)(b1 + o0);
#pragma unroll
    for (int i = 0; i < 4; ++i) {
      float4 hv;
      hv.x = fmaxf(acc[i][0] + bb.x, 0.f); hv.y = fmaxf(acc[i][1] + bb.y, 0.f);
      hv.z = fmaxf(acc[i][2] + bb.z, 0.f); hv.w = fmaxf(acc[i][3] + bb.w, 0.f);
      *(float4*)(sH + (r0 + i) * 132 + o0) = hv;
    }
  }
  __syncthreads();   // sW free, h1 visible

  // ---- layer 2: h2 = relu(h1 @ W2 + b2), W2 in 4 chunks of 32 rows ----
  float acc2[4][4] = {{0.f}};
  for (int c = 0; c < 4; ++c) {
    for (int e = t; e < 1024; e += 256)
      ((float4*)sW)[e] = ((const float4*)(w2t + c * 4096))[e];
    __syncthreads();
    const int kb = c * 32;
    for (int kk = 0; kk < 32; kk += 4) {
      float4 a[4], w[4];
#pragma unroll
      for (int i = 0; i < 4; ++i) a[i] = *(const float4*)(sH + (r0 + i) * 132 + kb + kk);
#pragma unroll
      for (int q = 0; q < 4; ++q) w[q] = *(const float4*)(sW + (kk + q) * 128 + o0);
#pragma unroll
      for (int i = 0; i < 4; ++i) {
        const float ak[4] = {a[i].x, a[i].y, a[i].z, a[i].w};
#pragma unroll
        for (int q = 0; q < 4; ++q) {
          acc2[i][0] += ak[q] * w[q].x; acc2[i][1] += ak[q] * w[q].y;
          acc2[i][2] += ak[q] * w[q].z; acc2[i][3] += ak[q] * w[q].w;
        }
      }
    }
    __syncthreads();  // chunk's sW reads done (last iter: sH reads done too)
  }
  // store h2 -> sH (reuse) ; load W3 -> sW[128][52] (cols 50,51 zero)
  {
    const float4 bb = *(const float4*)(b2 + o0);
#pragma unroll
    for (int i = 0; i < 4; ++i) {
      float4 hv;
      hv.x = fmaxf(acc2[i][0] + bb.x, 0.f); hv.y = fmaxf(acc2[i][1] + bb.y, 0.f);
      hv.z = fmaxf(acc2[i][2] + bb.z, 0.f); hv.w = fmaxf(acc2[i][3] + bb.w, 0.f);
      *(float4*)(sH + (r0 + i) * 132 + o0) = hv;
    }
  }
  for (int e = t; e < 128 * 52; e += 256) {
    int k = e / 52, o = e - k * 52;
    sW[e] = (o < 50) ? w3t[k * 50 + o] : 0.f;
  }
  __syncthreads();

  // ---- layer 3: out50 = h2 @ W3 + b3 ; 4 rows x 2 outs per thread ----
  {
    const int o3v = (t & 31) * 2;
    const bool valid = (o3v < 50);
    const int o3 = valid ? o3v : 48;
    float a3[4][2] = {{0.f}};
    for (int kk = 0; kk < 128; kk += 4) {
      float4 a[4]; float2 w[4];
#pragma unroll
      for (int i = 0; i < 4; ++i) a[i] = *(const float4*)(sH + (r0 + i) * 132 + kk);
#pragma unroll
      for (int q = 0; q < 4; ++q) w[q] = *(const float2*)(sW + (kk + q) * 52 + o3);
#pragma unroll
      for (int i = 0; i < 4; ++i) {
        const float ak[4] = {a[i].x, a[i].y, a[i].z, a[i].w};
#pragma unroll
        for (int q = 0; q < 4; ++q) {
          a3[i][0] += ak[q] * w[q].x;
          a3[i][1] += ak[q] * w[q].y;
        }
      }
    }
    if (valid) {
      const float bx = b3[o3], by = b3[o3 + 1];
#pragma unroll
      for (int i = 0; i < 4; ++i) {
        int g = base + r0 + i;
        x[g * 51 + o3]     = a3[i][0] + bx;
        x[g * 51 + o3 + 1] = a3[i][1] + by;
      }
    }
    if ((t & 31) == 31) {
#pragma unroll
      for (int i = 0; i < 4; ++i) {
        int g = base + r0 + i;
        x[g * 51 + 50] = data[g * 6 + 5];
      }
    }
  }
}

// ===========================================================================
// k_g1: per-batch GCN stack on past nodes, float4 k-loops (stride 68).
// ===========================================================================
template <int K, bool RELU>
__device__ __forceinline__ void gemm_tile68(const float* __restrict__ Am,
                                            const float* __restrict__ Bm,
                                            float* __restrict__ Cm, int t)
{
  const int r0 = (t >> 4) * 4, o0 = (t & 15) * 4;
  float acc[4][4] = {{0.f}};
  for (int kk = 0; kk < K; kk += 4) {
    float4 a[4], w[4];
#pragma unroll
    for (int i = 0; i < 4; ++i) a[i] = *(const float4*)(Am + (r0 + i) * 68 + kk);
#pragma unroll
    for (int q = 0; q < 4; ++q) w[q] = *(const float4*)(Bm + (kk + q) * 68 + o0);
#pragma unroll
    for (int i = 0; i < 4; ++i) {
      const float ak[4] = {a[i].x, a[i].y, a[i].z, a[i].w};
#pragma unroll
      for (int q = 0; q < 4; ++q) {
        acc[i][0] += ak[q] * w[q].x; acc[i][1] += ak[q] * w[q].y;
        acc[i][2] += ak[q] * w[q].z; acc[i][3] += ak[q] * w[q].w;
      }
    }
  }
#pragma unroll
  for (int i = 0; i < 4; ++i) {
#pragma unroll
    for (int j = 0; j < 4; ++j) {
      float v = acc[i][j];
      if (RELU) v = v > 0.f ? v : 0.f;
      Cm[(r0 + i) * 68 + o0 + j] = v;
    }
  }
}

__global__ __launch_bounds__(256) void k_g1(float* __restrict__ ws)
{
  __shared__ __align__(16) float B0[64 * 68];
  __shared__ __align__(16) float B1[64 * 68];
  __shared__ __align__(16) float B2[64 * 68];
  const int t = threadIdx.x, b = blockIdx.x;
  const float* x = ws + OFF_X;
  const float* an11 = ws + OFF_AN11;
  const float* g1at = ws + OFF_G1AT;
  const float* g1bt = ws + OFF_G1BT;
  float* x1 = ws + OFF_X1;

  for (int e = t; e < 64 * 51; e += 256) {
    int r = e / 51, c = e % 51;
    B0[r * 68 + c] = x[(b * 80 + r) * 51 + c];
  }
  for (int r = t; r < 64; r += 256) B0[r * 68 + 51] = 0.f;
  for (int e = t; e < 51 * 64; e += 256) B1[(e / 64) * 68 + (e & 63)] = g1at[e];
  for (int c = t; c < 64; c += 256) B1[51 * 68 + c] = 0.f;
  __syncthreads();
  gemm_tile68<52, false>(B0, B1, B2, t);        // t1 = sg1 @ W1aT   (64x64)
  __syncthreads();
  for (int e = t; e < 4096; e += 256) B1[(e >> 6) * 68 + (e & 63)] = an11[e];
  __syncthreads();
  gemm_tile68<64, true>(B1, B2, B0, t);         // P = relu(An @ t1)
  __syncthreads();
  gemm_tile68<64, false>(B1, B0, B2, t);        // Q = An @ P
  __syncthreads();
  for (int e = t; e < 64 * 50; e += 256) {
    int k = e / 50, o = e % 50;
    B0[k * 68 + o] = g1bt[e];
  }
  for (int k = t; k < 64; k += 256) { B0[k * 68 + 50] = 0.f; B0[k * 68 + 51] = 0.f; }
  __syncthreads();
  // x1 = Q @ W1bT  (64x50)
  {
    const int r0 = (t >> 4) * 4, o0 = (t & 15) * 4;
    float acc[4][4] = {{0.f}};
    for (int kk = 0; kk < 64; kk += 4) {
      float4 a[4], w[4];
#pragma unroll
      for (int i = 0; i < 4; ++i) a[i] = *(const float4*)(B2 + (r0 + i) * 68 + kk);
#pragma unroll
      for (int q = 0; q < 4; ++q) w[q] = *(const float4*)(B0 + (kk + q) * 68 + o0);
#pragma unroll
      for (int i = 0; i < 4; ++i) {
        const float ak[4] = {a[i].x, a[i].y, a[i].z, a[i].w};
#pragma unroll
        for (int q = 0; q < 4; ++q) {
          acc[i][0] += ak[q] * w[q].x; acc[i][1] += ak[q] * w[q].y;
          acc[i][2] += ak[q] * w[q].z; acc[i][3] += ak[q] * w[q].w;
        }
      }
    }
#pragma unroll
    for (int i = 0; i < 4; ++i) {
#pragma unroll
      for (int j = 0; j < 4; ++j) {
        int o = o0 + j;
        if (o < 50) x1[(b * 64 + r0 + i) * 50 + o] = acc[i][j];
      }
    }
  }
}

// ===========================================================================
// k_q: q decomposition + masked softmax over FUT axis + yh. stride 60.
// ===========================================================================
__global__ __launch_bounds__(256) void k_q(float* __restrict__ ws)
{
  __shared__ __align__(16) float Xp[64 * 60];
  __shared__ __align__(16) float Xf[16 * 60];
  __shared__ __align__(16) float Th[52 * 60];
  __shared__ __align__(16) float U[64 * 60];
  __shared__ float V[16 * 60];
  __shared__ float yv[64];
  __shared__ float sv[64];
  __shared__ float rv[16];
  __shared__ float al[16 * 64];
  __shared__ float mks[16 * 64];
  const int t = threadIdx.x, b = blockIdx.x;
  const float* x = ws + OFF_X;
  const float* x1 = ws + OFF_X1;
  const float* th = ws + OFF_TH;
  const float* mk = ws + OFF_MK;
  const float sc = (ws + OFF_SC)[0];
  float* yh = ws + OFF_YH;

  for (int e = t; e < 64 * 60; e += 256) {
    int r = e / 60, c = e - r * 60;
    Xp[e] = (c < 50) ? x1[(b * 64 + r) * 50 + c] : 0.f;
  }
  for (int e = t; e < 16 * 60; e += 256) {
    int r = e / 60, c = e - r * 60;
    Xf[e] = (c < 50) ? x[(b * 80 + 64 + r) * 51 + c] : 0.f;
  }
  for (int e = t; e < 52 * 60; e += 256) {
    int r = e / 60, c = e - r * 60;
    Th[e] = (r < 50 && c < 50) ? th[r * 50 + c] : 0.f;
  }
  for (int e = t; e < 1024; e += 256) mks[e] = mk[e];
  if (t < 64) yv[t] = x[(b * 80 + t) * 51 + 50];
  __syncthreads();

  // U = Xp @ Th (64x~52), V = Xf @ Th (16x~52)
  {
    const int r0 = (t >> 4) * 4;
    int o0 = (t & 15) * 4; if (o0 > 56) o0 = 56;   // clamp (dup stores benign)
    float acc[4][4] = {{0.f}};
    for (int kk = 0; kk < 52; kk += 4) {
      float4 a[4], w[4];
#pragma unroll
      for (int i = 0; i < 4; ++i) a[i] = *(const float4*)(Xp + (r0 + i) * 60 + kk);
#pragma unroll
      for (int q = 0; q < 4; ++q) w[q] = *(const float4*)(Th + (kk + q) * 60 + o0);
#pragma unroll
      for (int i = 0; i < 4; ++i) {
        const float ak[4] = {a[i].x, a[i].y, a[i].z, a[i].w};
#pragma unroll
        for (int q = 0; q < 4; ++q) {
          acc[i][0] += ak[q] * w[q].x; acc[i][1] += ak[q] * w[q].y;
          acc[i][2] += ak[q] * w[q].z; acc[i][3] += ak[q] * w[q].w;
        }
      }
    }
#pragma unroll
    for (int i = 0; i < 4; ++i)
      *(float4*)(U + (r0 + i) * 60 + o0) = make_float4(acc[i][0], acc[i][1], acc[i][2], acc[i][3]);
    // V rows (16): scalar, tiny
    const int jr = t >> 4;
    float accv[4] = {0.f, 0.f, 0.f, 0.f};
    for (int k = 0; k < 50; ++k) {
      float a = Xf[jr * 60 + k];
#pragma unroll
      for (int j = 0; j < 4; ++j) accv[j] += a * Th[k * 60 + o0 + j];
    }
#pragma unroll
    for (int j = 0; j < 4; ++j) V[jr * 60 + o0 + j] = accv[j];
  }
  __syncthreads();
  if (t < 64) {
    float s = 0.f;
    for (int k = 0; k < 50; ++k) s += U[t * 60 + k] * Xp[t * 60 + k];
    sv[t] = s;
  } else if (t < 80) {
    int j = t - 64; float s = 0.f;
    for (int k = 0; k < 50; ++k) s += V[j * 60 + k] * Xf[j * 60 + k];
    rv[j] = s;
  }
  __syncthreads();
  // logits al[j][i] = sc * (s_i + r_j - 2 * U_i . Xf_j)
  {
    const int i = t & 63;
    const int j0 = (t >> 6) * 4;
#pragma unroll
    for (int jj = 0; jj < 4; ++jj) {
      int j = j0 + jj;
      float d = 0.f;
      for (int kk = 0; kk < 52; kk += 4) {
        float4 u = *(const float4*)(U + i * 60 + kk);
        float4 f = *(const float4*)(Xf + j * 60 + kk);
        d += u.x * f.x + u.y * f.y + u.z * f.z + u.w * f.w;
      }
      al[j * 64 + i] = sc * (sv[i] + rv[j] - 2.f * d);
    }
  }
  __syncthreads();
  // softmax over j per (b,i); all-masked -> uniform 1/16
  if (t < 64) {
    const int i = t;
    float m = -3.4e38f;
#pragma unroll
    for (int j = 0; j < 16; ++j) {
      float v = (mks[j * 64 + i] != 0.f) ? al[j * 64 + i] : NEGBIG;
      m = fmaxf(m, v);
    }
    float s = 0.f; float ex[16];
#pragma unroll
    for (int j = 0; j < 16; ++j) {
      float v = (mks[j * 64 + i] != 0.f) ? al[j * 64 + i] : NEGBIG;
      ex[j] = expf(v - m); s += ex[j];
    }
    float inv = 1.f / s;
#pragma unroll
    for (int j = 0; j < 16; ++j) al[j * 64 + i] = ex[j] * inv;
  }
  __syncthreads();
  if (t < 16) {
    float s = 0.f;
    for (int i = 0; i < 64; ++i) s += al[t * 64 + i] * yv[i];
    yh[b * 16 + t] = s;
  }
}

// ===========================================================================
// k_g2 (unchanged from round 1 — tiny)
// ===========================================================================
__global__ __launch_bounds__(256) void k_g2(const float* __restrict__ wg2b,
                                            float* __restrict__ ws,
                                            float* __restrict__ out)
{
  __shared__ float X2[16 * 53];
  __shared__ __align__(16) float G[16 * 68];
  __shared__ float P[16 * 68];
  __shared__ float A22[256];
  __shared__ float wb[64];
  __shared__ float z[16];
  const int t = threadIdx.x, b = blockIdx.x;
  const float* x = ws + OFF_X;
  const float* yh = ws + OFF_YH;
  const float* an22 = ws + OFF_AN22;
  const float* g2at = ws + OFF_G2AT;

  for (int e = t; e < 16 * 51; e += 256) {
    int r = e / 51, c = e % 51;
    X2[r * 53 + c] = (c < 50) ? x[(b * 80 + 64 + r) * 51 + c] : yh[b * 16 + r];
  }
  for (int e = t; e < 256; e += 256) A22[e] = an22[e];
  if (t < 64) wb[t] = wg2b[t];
  __syncthreads();
  {
    const int j = t >> 4, o0 = (t & 15) * 4;
    float acc[4] = {0.f, 0.f, 0.f, 0.f};
    for (int k = 0; k < 51; ++k) {
      float a = X2[j * 53 + k];
      const float4 w = *(const float4*)(g2at + k * 64 + o0);
      acc[0] += a * w.x; acc[1] += a * w.y; acc[2] += a * w.z; acc[3] += a * w.w;
    }
#pragma unroll
    for (int q2 = 0; q2 < 4; ++q2) G[j * 68 + o0 + q2] = acc[q2];
  }
  __syncthreads();
  {
    const int j = t >> 4, o0 = (t & 15) * 4;
    float acc[4] = {0.f, 0.f, 0.f, 0.f};
    for (int k = 0; k < 16; ++k) {
      float a = A22[j * 16 + k];
      const float4 g4 = *(const float4*)(G + k * 68 + o0);
      acc[0] += a * g4.x; acc[1] += a * g4.y; acc[2] += a * g4.z; acc[3] += a * g4.w;
    }
#pragma unroll
    for (int q2 = 0; q2 < 4; ++q2) {
      float v = acc[q2];
      P[j * 68 + o0 + q2] = v > 0.f ? v : 0.f;
    }
  }
  __syncthreads();
  if (t < 16) {
    float s = 0.f;
    for (int o = 0; o < 64; ++o) s += P[t * 68 + o] * wb[o];
    z[t] = s;
  }
  __syncthreads();
  if (t < 16) {
    float s = 0.f;
#pragma unroll
    for (int k = 0; k < 16; ++k) s += A22[t * 16 + k] * z[k];
    out[OUT_OUT + b * 16 + t] = s;
  }
}

// ===========================================================================
// k_dist: pairwise distances; stride 60, float4 k-loop, coalesced stores.
// ===========================================================================
__global__ __launch_bounds__(256) void k_dist(float* __restrict__ ws,
                                              float* __restrict__ out)
{
  __shared__ __align__(16) float Xc[80 * 60];
  __shared__ float sq[80];
  const int t = threadIdx.x, b = blockIdx.x;
  const float* x = ws + OFF_X;
  const float* yh = ws + OFF_YH;
  float* dist = out + OUT_DIST + b * 6400;

  for (int e = t; e < 80 * 60; e += 256) {
    int n = e / 60, c = e - n * 60;
    float v = 0.f;
    if (c < 50)       v = x[(b * 80 + n) * 51 + c];
    else if (c == 50) v = (n < 64) ? x[(b * 80 + n) * 51 + 50] : yh[b * 16 + (n - 64)];
    Xc[e] = v;
  }
  __syncthreads();
  if (t < 80) {
    float s = 0.f;
    for (int c = 0; c < 51; ++c) { float v = Xc[t * 60 + c]; s += v * v; }
    sq[t] = s;
  }
  __syncthreads();
  const int n0 = (t >> 4) * 5;       // 16 groups x 5 rows
  const int mc = t & 15;             // cols mc + 16*j  (lane-contiguous stores)
  float acc[5][5] = {{0.f}};
  for (int kk = 0; kk < 52; kk += 4) {
    float4 a[5], bv[5];
#pragma unroll
    for (int i = 0; i < 5; ++i) a[i] = *(const float4*)(Xc + (n0 + i) * 60 + kk);
#pragma unroll
    for (int j = 0; j < 5; ++j) bv[j] = *(const float4*)(Xc + (mc + 16 * j) * 60 + kk);
#pragma unroll
    for (int i = 0; i < 5; ++i) {
#pragma unroll
      for (int j = 0; j < 5; ++j) {
        acc[i][j] += a[i].x * bv[j].x + a[i].y * bv[j].y +
                     a[i].z * bv[j].z + a[i].w * bv[j].w;
      }
    }
  }
#pragma unroll
  for (int i = 0; i < 5; ++i) {
#pragma unroll
    for (int j = 0; j < 5; ++j) {
      int m = mc + 16 * j;
      float d2 = sq[n0 + i] + sq[m] - 2.f * acc[i][j];
      d2 = d2 > 0.f ? d2 : 0.f;
      dist[(n0 + i) * 80 + m] = d2 > 0.f ? sqrtf(d2) : 0.f;
    }
  }
}

// ===========================================================================
extern "C" void kernel_launch(void* const* d_in, const int* in_sizes, int n_in,
                              void* d_out, int out_size, void* d_ws, size_t ws_size,
                              hipStream_t stream)
{
  const float* data = (const float*)d_in[0];
  const float* emb0 = (const float*)d_in[1];
  const float* emb1 = (const float*)d_in[2];
  const float* emb2 = (const float*)d_in[3];
  const float* w1   = (const float*)d_in[4];
  const float* b1   = (const float*)d_in[5];
  const float* w2   = (const float*)d_in[6];
  const float* b2   = (const float*)d_in[7];
  const float* w3   = (const float*)d_in[8];
  const float* b3   = (const float*)d_in[9];
  const float* M    = (const float*)d_in[10];
  const float* wg1a = (const float*)d_in[11];
  const float* wg1b = (const float*)d_in[12];
  const float* Wk   = (const float*)d_in[13];
  const float* smo  = (const float*)d_in[14];
  const float* wg2a = (const float*)d_in[15];
  const float* wg2b = (const float*)d_in[16];
  float* ws  = (float*)d_ws;
  float* out = (float*)d_out;

  k_prep<<<dim3(4),    dim3(256), 0, stream>>>(M, Wk, smo, w1, w2, w3, wg1a, wg1b, wg2a, ws, out);
  k_mlp <<<dim3(2560), dim3(256), 0, stream>>>(data, emb0, emb1, emb2, b1, b2, b3, ws);
  k_g1  <<<dim3(1024), dim3(256), 0, stream>>>(ws);
  k_q   <<<dim3(1024), dim3(256), 0, stream>>>(ws);
  k_g2  <<<dim3(1024), dim3(256), 0, stream>>>(wg2b, ws, out);
  k_dist<<<dim3(1024), dim3(256), 0, stream>>>(ws, out);
}